// Round 2
// baseline (93.094 us; speedup 1.0000x reference)
//
#include <hip/hip_runtime.h>
#include <hip/hip_bf16.h>
#include <math.h>

typedef __attribute__((ext_vector_type(8))) short bf16x8;
typedef __attribute__((ext_vector_type(4))) float f32x4;

#define NB 16
#define NM 16
#define NN 32
#define NT 80
#define TC 20   // timesteps per partial block
#define NP 4    // partial blocks per (b,m)

// ---- d_ws float layout ----
// [0..7]   : softplus weights (from weights_kernel)
// [16 + bm*1056 + p*256 + col]          : partial feat sums (sum over TC t of max-over-n)
// [16 + bm*1056 + 1024 + p*8 + k]      : partial scalars k={0:spd,1:|acc|,2:|jerk|,3:|lat|,4:egosum,5:coll}
#define WS_WTS 0
#define WS_BASE 16
#define WS_BM_STRIDE 1056
#define WS_SC_OFF 1024

__device__ __forceinline__ short f2bf(float f) {
  unsigned u = __float_as_uint(f);
  u += 0x7fffu + ((u >> 16) & 1u);
  return (short)(u >> 16);
}

// ---------------- kernel 0: weights head (data-independent: enc_in = ones) ---
__global__ void weights_kernel(const float* __restrict__ wd_w1,
                               const float* __restrict__ wd_b1,
                               const float* __restrict__ wd_w2,
                               const float* __restrict__ wd_b2,
                               float* __restrict__ ws,
                               float* __restrict__ out) {
  __shared__ float sh[64];
  int j = threadIdx.x;
  if (j < 64) {
    float acc = wd_b1[j];
    for (int i = 0; i < 256; ++i) acc += wd_w1[i * 64 + j];
    sh[j] = acc > 0.f ? acc : expm1f(acc);  // elu
  }
  __syncthreads();
  if (j < 8) {
    float acc = wd_b2[j];
    for (int k = 0; k < 64; ++k) acc += sh[k] * wd_w2[k * 8 + j];
    float sp = log1pf(__expf(acc));  // softplus
    ws[WS_WTS + j] = sp;
    for (int b = 0; b < NB; ++b) out[NB * NM + b * 8 + j] = sp;  // weights output
  }
}

// ---------------- kernel 1: partial encoder/feature kernel ------------------
// grid = NB*NM*NP, 256 threads. Block (bm, p) handles t in [p*TC, p*TC+TC).
__global__ __launch_bounds__(256, 4) void score_partial(
    const float* __restrict__ ego_traj,      // [B][M][T][6]
    const float* __restrict__ agents_traj,   // [B][M][N][T][3]
    const float* __restrict__ agents_states, // [B][N][11]
    const float* __restrict__ enc_w1, const float* __restrict__ enc_b1,
    const float* __restrict__ enc_w2,
    float* __restrict__ ws)
{
  __shared__ float s_traj[TC + 2][NN][3];               // rows: local t0-1 .. t0+TC
  __shared__ __align__(16) short s_hidden[4][NN * 64];  // 4 ping-pong bf16 tiles
  __shared__ float s_ego[TC][5];                        // ex,ey,eh,evx,evy
  __shared__ float s_acc[TC + 2];                       // acc, +1 offset like traj
  __shared__ float s_spd[TC], s_lat[TC], s_egos[TC];
  __shared__ float s_mask[NN];
  __shared__ float s_collred[NN];

  const int bid = blockIdx.x;
  const int bm = bid >> 2;
  const int p = bid & 3;
  const int t0 = p * TC;
  const int b = bm >> 4;
  const int tid = threadIdx.x;
  const int lane = tid & 63;
  const int wv = tid >> 6;

  float* ws_bm = ws + WS_BASE + (size_t)bm * WS_BM_STRIDE;

  // ---- stage agents_traj rows [t0-1 .. t0+TC-1] (row 0 = t0-1; unused for p==0) ----
  {
    const float* src = agents_traj + (size_t)bm * (NN * NT * 3);
    const int tg0 = (p == 0) ? 0 : (t0 - 1);
    const int rowofs = (p == 0) ? 1 : 0;
    const int LD = (TC + 1) * 3;  // 63 contiguous floats per agent
    for (int i = tid; i < NN * LD; i += 256) {
      int n = i / LD;
      int r = i - n * LD;
      int lt = r / 3;
      int c = r - lt * 3;
      s_traj[lt + rowofs][n][c] = src[n * (NT * 3) + tg0 * 3 + r];
    }
  }
  // ---- ego staging + agent mask ----
  if (tid < TC) {
    int i = tid;
    const float* e = ego_traj + ((size_t)bm * NT + (t0 + i)) * 6;
    float ex = e[0], ey = e[1], eh = e[2], spd = e[3], acc = e[4], cur = e[5];
    s_ego[i][0] = ex; s_ego[i][1] = ey; s_ego[i][2] = eh;
    s_ego[i][3] = spd * __cosf(eh);
    s_ego[i][4] = spd * __sinf(eh);
    s_spd[i] = spd;
    s_acc[i + 1] = acc;
    s_lat[i] = fabsf(spd * spd * cur);
    s_egos[i] = ex + ey + eh + spd + acc + cur;
  } else if (tid == TC) {
    int tp = (p == 0) ? 0 : (t0 - 1);
    s_acc[0] = ego_traj[((size_t)bm * NT + tp) * 6 + 4];
  } else if (tid >= 64 && tid < 64 + NN) {
    int n = tid - 64;
    const float* st = agents_states + ((size_t)b * NN + n) * 11;
    float s = 0.f;
    for (int i = 0; i < 11; ++i) s += st[i];
    s_mask[n] = (s != 0.f) ? 1.f : 0.f;
  }
  __syncthreads();

  // ---- hard-feature partial sums (raw sums; combine kernel does mean/clip) ----
  if (tid == 0) {
    float s = 0.f; for (int i = 0; i < TC; ++i) s += s_spd[i];
    ws_bm[WS_SC_OFF + p * 8 + 0] = s;
  } else if (tid == 1) {
    float s = 0.f; for (int i = 0; i < TC; ++i) s += fabsf(s_acc[i + 1]);
    ws_bm[WS_SC_OFF + p * 8 + 1] = s;
  } else if (tid == 2) {
    float s = 0.f;
    for (int i = 0; i < TC; ++i) {
      int ia = (p == 0 && i == 0) ? 2 : (i + 1);  // global th = t?t:1
      s += fabsf((s_acc[ia] - s_acc[ia - 1]) * 10.f);
    }
    ws_bm[WS_SC_OFF + p * 8 + 2] = s;
  } else if (tid == 3) {
    float s = 0.f; for (int i = 0; i < TC; ++i) s += s_lat[i];
    ws_bm[WS_SC_OFF + p * 8 + 3] = s;
  } else if (tid == 4) {
    float s = 0.f; for (int i = 0; i < TC; ++i) s += s_egos[i];
    ws_bm[WS_SC_OFF + p * 8 + 4] = s;
  }

  const int n = tid >> 3;   // agent for GEMM1
  const int jg = tid & 7;
  const int j0 = jg * 8;
  const float mask_n = s_mask[n];

  // enc_w1 rows 0..4 (rel features) -> registers
  float w1r[5][8];
#pragma unroll
  for (int i = 0; i < 5; ++i)
#pragma unroll
    for (int jj = 0; jj < 8; ++jj)
      w1r[i][jj] = enc_w1[i * 64 + j0 + jj];

  // baseB = mask * (agent_states[6:11] @ enc_w1[5:10]) + enc_b1
  float baseB[8];
  {
    const float* st = agents_states + ((size_t)b * NN + n) * 11 + 6;
    float a0 = st[0], a1 = st[1], a2 = st[2], a3 = st[3], a4 = st[4];
#pragma unroll
    for (int jj = 0; jj < 8; ++jj) {
      float acc = a0 * enc_w1[5 * 64 + j0 + jj] + a1 * enc_w1[6 * 64 + j0 + jj] +
                  a2 * enc_w1[7 * 64 + j0 + jj] + a3 * enc_w1[8 * 64 + j0 + jj] +
                  a4 * enc_w1[9 * 64 + j0 + jj];
      baseB[jj] = mask_n * acc + enc_b1[j0 + jj];
    }
  }

  // enc_w2 B-fragments: wave wv owns cols [wv*64, wv*64+64)
  bf16x8 Bf[4][2];
  {
    const int colb = lane & 15;
    const int krow = (lane >> 4) * 8;
#pragma unroll
    for (int ct = 0; ct < 4; ++ct) {
      int col = wv * 64 + ct * 16 + colb;
#pragma unroll
      for (int kt = 0; kt < 2; ++kt) {
#pragma unroll
        for (int j = 0; j < 8; ++j) {
          int k = kt * 32 + krow + j;
          Bf[ct][kt][j] = f2bf(enc_w2[k * 256 + col]);
        }
      }
    }
  }

  // swizzled hidden-tile addresses (G4: byte ^= (row&7)<<4)
  const int wbyte = (n * 128 + j0 * 2) ^ ((n & 7) << 4);
  int abyte[2][2];
  {
    int nb = lane & 15;
    int kb = (lane >> 4) * 16;
#pragma unroll
    for (int rt = 0; rt < 2; ++rt) {
      int row = rt * 16 + nb;
#pragma unroll
      for (int kt = 0; kt < 2; ++kt)
        abyte[rt][kt] = (row * 128 + kt * 64 + kb) ^ ((row & 7) << 4);
    }
  }

  float collacc = 0.f;

  // rel features + GEMM1(K=5) + relu + bf16 -> swizzled LDS tile (local t index i)
  auto compute_hidden = [&](int i, int buf) {
    float ex = s_ego[i][0], ey = s_ego[i][1], eh = s_ego[i][2];
    float evx = s_ego[i][3], evy = s_ego[i][4];
    const int lt = i + 1;
    float ax = s_traj[lt][n][0], ay = s_traj[lt][n][1], ah = s_traj[lt][n][2];
    const int ia = (p == 0 && i == 0) ? 2 : lt;  // row of global th = t?t:1
    float avx = (s_traj[ia][n][0] - s_traj[ia - 1][n][0]) * 10.f;
    float avy = (s_traj[ia][n][1] - s_traj[ia - 1][n][1]) * 10.f;
    float ryr = ah - eh;
    float w = ryr - 6.283185307179586f * rintf(ryr * 0.15915494309189535f);
    float cy = __cosf(ryr), sy = __sinf(ryr);
    float dx = ax - ex, dy = ay - ey;
    float r0 = dx * cy * mask_n;
    float r1 = dy * sy * mask_n;
    float r2 = w * mask_n;
    float r3 = (avx - evx) * cy * mask_n;
    float r4 = (avy - evy) * sy * mask_n;
    if (jg == 0) collacc += __expf(-0.2f * (dx * dx + dy * dy)) * mask_n;
    bf16x8 hv;
#pragma unroll
    for (int jj = 0; jj < 8; ++jj) {
      float pre = baseB[jj] + r0 * w1r[0][jj] + r1 * w1r[1][jj] +
                  r2 * w1r[2][jj] + r3 * w1r[3][jj] + r4 * w1r[4][jj];
      hv[jj] = f2bf(fmaxf(pre, 0.f));
    }
    *reinterpret_cast<bf16x8*>(reinterpret_cast<char*>(&s_hidden[buf][0]) + wbyte) = hv;
  };

  compute_hidden(0, 0);
  compute_hidden(1, 1);
  __syncthreads();

  float macc[4] = {0.f, 0.f, 0.f, 0.f};

  for (int i = 0; i < TC; i += 2) {
    const char* hA = reinterpret_cast<const char*>(&s_hidden[i & 3][0]);
    const char* hB = reinterpret_cast<const char*>(&s_hidden[(i + 1) & 3][0]);
    bf16x8 a00 = *reinterpret_cast<const bf16x8*>(hA + abyte[0][0]);
    bf16x8 a01 = *reinterpret_cast<const bf16x8*>(hA + abyte[0][1]);
    bf16x8 a10 = *reinterpret_cast<const bf16x8*>(hA + abyte[1][0]);
    bf16x8 a11 = *reinterpret_cast<const bf16x8*>(hA + abyte[1][1]);
    bf16x8 b00 = *reinterpret_cast<const bf16x8*>(hB + abyte[0][0]);
    bf16x8 b01 = *reinterpret_cast<const bf16x8*>(hB + abyte[0][1]);
    bf16x8 b10 = *reinterpret_cast<const bf16x8*>(hB + abyte[1][0]);
    bf16x8 b11 = *reinterpret_cast<const bf16x8*>(hB + abyte[1][1]);

    if (i + 2 < TC) compute_hidden(i + 2, (i + 2) & 3);
    if (i + 3 < TC) compute_hidden(i + 3, (i + 3) & 3);

#pragma unroll
    for (int ct = 0; ct < 4; ++ct) {
      f32x4 c0 = {0.f, 0.f, 0.f, 0.f}, c1 = {0.f, 0.f, 0.f, 0.f};
      f32x4 d0 = {0.f, 0.f, 0.f, 0.f}, d1 = {0.f, 0.f, 0.f, 0.f};
      c0 = __builtin_amdgcn_mfma_f32_16x16x32_bf16(a00, Bf[ct][0], c0, 0, 0, 0);
      d0 = __builtin_amdgcn_mfma_f32_16x16x32_bf16(b00, Bf[ct][0], d0, 0, 0, 0);
      c0 = __builtin_amdgcn_mfma_f32_16x16x32_bf16(a01, Bf[ct][1], c0, 0, 0, 0);
      d0 = __builtin_amdgcn_mfma_f32_16x16x32_bf16(b01, Bf[ct][1], d0, 0, 0, 0);
      c1 = __builtin_amdgcn_mfma_f32_16x16x32_bf16(a10, Bf[ct][0], c1, 0, 0, 0);
      d1 = __builtin_amdgcn_mfma_f32_16x16x32_bf16(b10, Bf[ct][0], d1, 0, 0, 0);
      c1 = __builtin_amdgcn_mfma_f32_16x16x32_bf16(a11, Bf[ct][1], c1, 0, 0, 0);
      d1 = __builtin_amdgcn_mfma_f32_16x16x32_bf16(b11, Bf[ct][1], d1, 0, 0, 0);
      float v = fmaxf(fmaxf(fmaxf(c0[0], c1[0]), fmaxf(c0[1], c1[1])),
                      fmaxf(fmaxf(c0[2], c1[2]), fmaxf(c0[3], c1[3])));
      v = fmaxf(v, __shfl_xor(v, 16));
      v = fmaxf(v, __shfl_xor(v, 32));
      float u = fmaxf(fmaxf(fmaxf(d0[0], d1[0]), fmaxf(d0[1], d1[1])),
                      fmaxf(fmaxf(d0[2], d1[2]), fmaxf(d0[3], d1[3])));
      u = fmaxf(u, __shfl_xor(u, 16));
      u = fmaxf(u, __shfl_xor(u, 32));
      macc[ct] += v + u;
    }
    __syncthreads();
  }

  // ---- partial outputs ----
  if (lane < 16) {
#pragma unroll
    for (int ct = 0; ct < 4; ++ct)
      ws_bm[p * 256 + wv * 64 + ct * 16 + lane] = macc[ct];
  }
  if (jg == 0) s_collred[n] = collacc;
  __syncthreads();
  if (tid == 0) {
    float c = 0.f;
    for (int i = 0; i < NN; ++i) c += s_collred[i];
    ws_bm[WS_SC_OFF + p * 8 + 5] = c;
  }
}

// ---------------- kernel 2: combine + decoder + score -----------------------
__global__ void combine_kernel(const float* __restrict__ ws,
                               const float* __restrict__ enc_b2,
                               const float* __restrict__ dec_w1,
                               const float* __restrict__ dec_b1,
                               const float* __restrict__ dec_w2,
                               const float* __restrict__ dec_b2,
                               float* __restrict__ out_scores) {
  __shared__ float s_feat[256];
  __shared__ float s_dh[64];
  __shared__ float s_hard[4];
  __shared__ float s_inter[4];
  __shared__ float s_mc[2];  // egosum, coll
  const int bm = blockIdx.x;
  const int tid = threadIdx.x;  // 64 threads
  const float* wb = ws + WS_BASE + (size_t)bm * WS_BM_STRIDE;

  for (int c = tid; c < 256; c += 64) {
    float f = wb[c] + wb[256 + c] + wb[512 + c] + wb[768 + c];
    s_feat[c] = f * (1.f / NT) + enc_b2[c];
  }
  const float* sc = wb + WS_SC_OFF;
  if (tid < 6) {
    float s = sc[tid] + sc[8 + tid] + sc[16 + tid] + sc[24 + tid];
    if (tid == 0) s_hard[0] = -fminf(fmaxf(s * (1.f / NT), 0.f), 15.f) * (1.f / 15.f);
    if (tid == 1) s_hard[1] = fminf(fmaxf(s * (1.f / NT), 0.f), 4.f) * 0.25f;
    if (tid == 2) s_hard[2] = fminf(fmaxf(s * (1.f / NT), 0.f), 6.f) * (1.f / 6.f);
    if (tid == 3) s_hard[3] = fminf(fmaxf(s * (1.f / NT), 0.f), 5.f) * 0.2f;
    if (tid == 4) s_mc[0] = s;
    if (tid == 5) s_mc[1] = s;
  }
  __syncthreads();

  {
    float a0 = 0.f, a1 = 0.f, a2 = 0.f, a3 = 0.f;
    for (int i = 0; i < 256; i += 4) {
      a0 += s_feat[i + 0] * dec_w1[(i + 0) * 64 + tid];
      a1 += s_feat[i + 1] * dec_w1[(i + 1) * 64 + tid];
      a2 += s_feat[i + 2] * dec_w1[(i + 2) * 64 + tid];
      a3 += s_feat[i + 3] * dec_w1[(i + 3) * 64 + tid];
    }
    float acc = dec_b1[tid] + ((a0 + a1) + (a2 + a3));
    s_dh[tid] = acc > 0.f ? acc : expm1f(acc);  // elu
  }
  __syncthreads();

  if (tid < 4) {
    float acc = dec_b2[tid];
    for (int k = 0; k < 64; ++k) acc += s_dh[k] * dec_w2[k * 4 + tid];
    s_inter[tid] = 1.f / (1.f + __expf(-acc));  // sigmoid
  }
  __syncthreads();

  if (tid == 0) {
    const float* wts = ws + WS_WTS;
    float scv = 0.f;
#pragma unroll
    for (int i = 0; i < 4; ++i) scv += s_hard[i] * wts[i];
#pragma unroll
    for (int i = 0; i < 4; ++i) scv += s_inter[i] * wts[4 + i];
    scv = -scv - 10.f * s_mc[1];
    if (s_mc[0] == 0.f) scv = -INFINITY;
    out_scores[bm] = scv;
  }
}

extern "C" void kernel_launch(void* const* d_in, const int* in_sizes, int n_in,
                              void* d_out, int out_size, void* d_ws, size_t ws_size,
                              hipStream_t stream) {
  const float* ego_traj      = (const float*)d_in[0];
  const float* agents_traj   = (const float*)d_in[2];
  const float* agents_states = (const float*)d_in[3];
  const float* enc_w1 = (const float*)d_in[4];
  const float* enc_b1 = (const float*)d_in[5];
  const float* enc_w2 = (const float*)d_in[6];
  const float* enc_b2 = (const float*)d_in[7];
  const float* dec_w1 = (const float*)d_in[8];
  const float* dec_b1 = (const float*)d_in[9];
  const float* dec_w2 = (const float*)d_in[10];
  const float* dec_b2 = (const float*)d_in[11];
  const float* wd_w1 = (const float*)d_in[12];
  const float* wd_b1 = (const float*)d_in[13];
  const float* wd_w2 = (const float*)d_in[14];
  const float* wd_b2 = (const float*)d_in[15];

  float* out = (float*)d_out;
  float* ws = (float*)d_ws;

  weights_kernel<<<1, 64, 0, stream>>>(wd_w1, wd_b1, wd_w2, wd_b2, ws, out);
  score_partial<<<NB * NM * NP, 256, 0, stream>>>(
      ego_traj, agents_traj, agents_states, enc_w1, enc_b1, enc_w2, ws);
  combine_kernel<<<NB * NM, 64, 0, stream>>>(
      ws, enc_b2, dec_w1, dec_b1, dec_w2, dec_b2, out);
}

// Round 3
// 64.746 us; speedup vs baseline: 1.4378x; 1.4378x over previous
//
#include <hip/hip_runtime.h>
#include <hip/hip_bf16.h>
#include <math.h>

typedef __attribute__((ext_vector_type(8))) short bf16x8;
typedef __attribute__((ext_vector_type(4))) float f32x4;

#define NB 16
#define NM 16
#define NN 32
#define NT 80
#define TC 20   // timesteps per partial block
#define NP 4    // partial blocks per (b,m)

// ---- d_ws float layout ----
#define WS_WTS 0
#define WS_BASE 16
#define WS_BM_STRIDE 1056
#define WS_SC_OFF 1024

__device__ __forceinline__ short f2bf(float f) {
  unsigned u = __float_as_uint(f);
  u += 0x7fffu + ((u >> 16) & 1u);
  return (short)(u >> 16);
}

// ---------------- kernel 0: weights head (data-independent: enc_in = ones) ---
__global__ void weights_kernel(const float* __restrict__ wd_w1,
                               const float* __restrict__ wd_b1,
                               const float* __restrict__ wd_w2,
                               const float* __restrict__ wd_b2,
                               float* __restrict__ ws,
                               float* __restrict__ out) {
  __shared__ float sh[64];
  int j = threadIdx.x;
  if (j < 64) {
    float acc = wd_b1[j];
    for (int i = 0; i < 256; ++i) acc += wd_w1[i * 64 + j];
    sh[j] = acc > 0.f ? acc : expm1f(acc);  // elu
  }
  __syncthreads();
  if (j < 8) {
    float acc = wd_b2[j];
    for (int k = 0; k < 64; ++k) acc += sh[k] * wd_w2[k * 8 + j];
    float sp = log1pf(__expf(acc));  // softplus
    ws[WS_WTS + j] = sp;
    for (int b = 0; b < NB; ++b) out[NB * NM + b * 8 + j] = sp;  // weights output
  }
}

// ---------------- kernel 1: partial encoder/feature kernel ------------------
// grid = NB*NM*NP, 256 threads. Block (bm, p) handles t in [p*TC, p*TC+TC).
// Single-t ping-pong loop (R0 structure, 96 VGPR — no spill), NO tight reg cap.
__global__ __launch_bounds__(256, 1) void score_partial(
    const float* __restrict__ ego_traj,      // [B][M][T][6]
    const float* __restrict__ agents_traj,   // [B][M][N][T][3]
    const float* __restrict__ agents_states, // [B][N][11]
    const float* __restrict__ enc_w1, const float* __restrict__ enc_b1,
    const float* __restrict__ enc_w2,
    float* __restrict__ ws)
{
  __shared__ float s_traj[TC + 2][NN][3];               // rows: local t0-1 .. t0+TC-1
  __shared__ __align__(16) short s_hidden[2][NN * 64];  // 2 ping-pong bf16 tiles
  __shared__ float s_ego[TC][5];                        // ex,ey,eh,evx,evy
  __shared__ float s_acc[TC + 2];
  __shared__ float s_spd[TC], s_lat[TC], s_egos[TC];
  __shared__ float s_mask[NN];
  __shared__ float s_collred[NN];

  const int bid = blockIdx.x;
  const int bm = bid >> 2;
  const int p = bid & 3;
  const int t0 = p * TC;
  const int b = bm >> 4;
  const int tid = threadIdx.x;
  const int lane = tid & 63;
  const int wv = tid >> 6;

  float* ws_bm = ws + WS_BASE + (size_t)bm * WS_BM_STRIDE;

  // ---- stage agents_traj rows [t0-1 .. t0+TC-1] (row 0 = t0-1; dup for p==0) ----
  {
    const float* src = agents_traj + (size_t)bm * (NN * NT * 3);
    const int tg0 = (p == 0) ? 0 : (t0 - 1);
    const int rowofs = (p == 0) ? 1 : 0;
    const int LD = (TC + 1) * 3;  // 63 contiguous floats per agent
    for (int i = tid; i < NN * LD; i += 256) {
      int n = i / LD;
      int r = i - n * LD;
      int lt = r / 3;
      int c = r - lt * 3;
      s_traj[lt + rowofs][n][c] = src[n * (NT * 3) + tg0 * 3 + r];
    }
  }
  // ---- ego staging + agent mask ----
  if (tid < TC) {
    int i = tid;
    const float* e = ego_traj + ((size_t)bm * NT + (t0 + i)) * 6;
    float ex = e[0], ey = e[1], eh = e[2], spd = e[3], acc = e[4], cur = e[5];
    s_ego[i][0] = ex; s_ego[i][1] = ey; s_ego[i][2] = eh;
    s_ego[i][3] = spd * __cosf(eh);
    s_ego[i][4] = spd * __sinf(eh);
    s_spd[i] = spd;
    s_acc[i + 1] = acc;
    s_lat[i] = fabsf(spd * spd * cur);
    s_egos[i] = ex + ey + eh + spd + acc + cur;
  } else if (tid == TC) {
    int tp = (p == 0) ? 0 : (t0 - 1);
    s_acc[0] = ego_traj[((size_t)bm * NT + tp) * 6 + 4];
  } else if (tid >= 64 && tid < 64 + NN) {
    int n = tid - 64;
    const float* st = agents_states + ((size_t)b * NN + n) * 11;
    float s = 0.f;
    for (int i = 0; i < 11; ++i) s += st[i];
    s_mask[n] = (s != 0.f) ? 1.f : 0.f;
  }
  __syncthreads();

  // ---- hard-feature partial sums (raw sums; combine kernel does mean/clip) ----
  if (tid == 0) {
    float s = 0.f; for (int i = 0; i < TC; ++i) s += s_spd[i];
    ws_bm[WS_SC_OFF + p * 8 + 0] = s;
  } else if (tid == 1) {
    float s = 0.f; for (int i = 0; i < TC; ++i) s += fabsf(s_acc[i + 1]);
    ws_bm[WS_SC_OFF + p * 8 + 1] = s;
  } else if (tid == 2) {
    float s = 0.f;
    for (int i = 0; i < TC; ++i) {
      int ia = (p == 0 && i == 0) ? 2 : (i + 1);  // global th = t?t:1
      s += fabsf((s_acc[ia] - s_acc[ia - 1]) * 10.f);
    }
    ws_bm[WS_SC_OFF + p * 8 + 2] = s;
  } else if (tid == 3) {
    float s = 0.f; for (int i = 0; i < TC; ++i) s += s_lat[i];
    ws_bm[WS_SC_OFF + p * 8 + 3] = s;
  } else if (tid == 4) {
    float s = 0.f; for (int i = 0; i < TC; ++i) s += s_egos[i];
    ws_bm[WS_SC_OFF + p * 8 + 4] = s;
  }

  const int n = tid >> 3;   // agent for GEMM1
  const int jg = tid & 7;
  const int j0 = jg * 8;
  const float mask_n = s_mask[n];

  // enc_w1 rows 0..4 (rel features) -> registers
  float w1r[5][8];
#pragma unroll
  for (int i = 0; i < 5; ++i)
#pragma unroll
    for (int jj = 0; jj < 8; ++jj)
      w1r[i][jj] = enc_w1[i * 64 + j0 + jj];

  // baseB = mask * (agent_states[6:11] @ enc_w1[5:10]) + enc_b1
  float baseB[8];
  {
    const float* st = agents_states + ((size_t)b * NN + n) * 11 + 6;
    float a0 = st[0], a1 = st[1], a2 = st[2], a3 = st[3], a4 = st[4];
#pragma unroll
    for (int jj = 0; jj < 8; ++jj) {
      float acc = a0 * enc_w1[5 * 64 + j0 + jj] + a1 * enc_w1[6 * 64 + j0 + jj] +
                  a2 * enc_w1[7 * 64 + j0 + jj] + a3 * enc_w1[8 * 64 + j0 + jj] +
                  a4 * enc_w1[9 * 64 + j0 + jj];
      baseB[jj] = mask_n * acc + enc_b1[j0 + jj];
    }
  }

  // enc_w2 B-fragments: wave wv owns cols [wv*64, wv*64+64)
  bf16x8 Bf[4][2];
  {
    const int colb = lane & 15;
    const int krow = (lane >> 4) * 8;
#pragma unroll
    for (int ct = 0; ct < 4; ++ct) {
      int col = wv * 64 + ct * 16 + colb;
#pragma unroll
      for (int kt = 0; kt < 2; ++kt) {
#pragma unroll
        for (int j = 0; j < 8; ++j) {
          int k = kt * 32 + krow + j;
          Bf[ct][kt][j] = f2bf(enc_w2[k * 256 + col]);
        }
      }
    }
  }

  // swizzled hidden-tile addresses (G4: byte ^= (row&7)<<4)
  const int wbyte = (n * 128 + j0 * 2) ^ ((n & 7) << 4);
  int abyte[2][2];
  {
    int nb = lane & 15;
    int kb = (lane >> 4) * 16;
#pragma unroll
    for (int rt = 0; rt < 2; ++rt) {
      int row = rt * 16 + nb;
#pragma unroll
      for (int kt = 0; kt < 2; ++kt)
        abyte[rt][kt] = (row * 128 + kt * 64 + kb) ^ ((row & 7) << 4);
    }
  }

  float collacc = 0.f;

  // rel features + GEMM1(K=5) + relu + bf16 -> swizzled LDS tile (local t index i)
  auto compute_hidden = [&](int i, int buf) {
    float ex = s_ego[i][0], ey = s_ego[i][1], eh = s_ego[i][2];
    float evx = s_ego[i][3], evy = s_ego[i][4];
    const int lt = i + 1;
    float ax = s_traj[lt][n][0], ay = s_traj[lt][n][1], ah = s_traj[lt][n][2];
    const int ia = (p == 0 && i == 0) ? 2 : lt;  // row of global th = t?t:1
    float avx = (s_traj[ia][n][0] - s_traj[ia - 1][n][0]) * 10.f;
    float avy = (s_traj[ia][n][1] - s_traj[ia - 1][n][1]) * 10.f;
    float ryr = ah - eh;
    float w = ryr - 6.283185307179586f * rintf(ryr * 0.15915494309189535f);
    float cy = __cosf(ryr), sy = __sinf(ryr);
    float dx = ax - ex, dy = ay - ey;
    float r0 = dx * cy * mask_n;
    float r1 = dy * sy * mask_n;
    float r2 = w * mask_n;
    float r3 = (avx - evx) * cy * mask_n;
    float r4 = (avy - evy) * sy * mask_n;
    if (jg == 0) collacc += __expf(-0.2f * (dx * dx + dy * dy)) * mask_n;
    bf16x8 hv;
#pragma unroll
    for (int jj = 0; jj < 8; ++jj) {
      float pre = baseB[jj] + r0 * w1r[0][jj] + r1 * w1r[1][jj] +
                  r2 * w1r[2][jj] + r3 * w1r[3][jj] + r4 * w1r[4][jj];
      hv[jj] = f2bf(fmaxf(pre, 0.f));
    }
    *reinterpret_cast<bf16x8*>(reinterpret_cast<char*>(&s_hidden[buf][0]) + wbyte) = hv;
  };

  compute_hidden(0, 0);
  __syncthreads();

  float macc[4] = {0.f, 0.f, 0.f, 0.f};

  for (int i = 0; i < TC; ++i) {
    const int buf = i & 1;
    const char* hb = reinterpret_cast<const char*>(&s_hidden[buf][0]);
    bf16x8 a00 = *reinterpret_cast<const bf16x8*>(hb + abyte[0][0]);
    bf16x8 a01 = *reinterpret_cast<const bf16x8*>(hb + abyte[0][1]);
    bf16x8 a10 = *reinterpret_cast<const bf16x8*>(hb + abyte[1][0]);
    bf16x8 a11 = *reinterpret_cast<const bf16x8*>(hb + abyte[1][1]);

    if (i + 1 < TC) compute_hidden(i + 1, buf ^ 1);  // ping-pong overlap

#pragma unroll
    for (int ct = 0; ct < 4; ++ct) {
      f32x4 c0 = {0.f, 0.f, 0.f, 0.f}, c1 = {0.f, 0.f, 0.f, 0.f};
      c0 = __builtin_amdgcn_mfma_f32_16x16x32_bf16(a00, Bf[ct][0], c0, 0, 0, 0);
      c0 = __builtin_amdgcn_mfma_f32_16x16x32_bf16(a01, Bf[ct][1], c0, 0, 0, 0);
      c1 = __builtin_amdgcn_mfma_f32_16x16x32_bf16(a10, Bf[ct][0], c1, 0, 0, 0);
      c1 = __builtin_amdgcn_mfma_f32_16x16x32_bf16(a11, Bf[ct][1], c1, 0, 0, 0);
      float v = fmaxf(fmaxf(fmaxf(c0[0], c1[0]), fmaxf(c0[1], c1[1])),
                      fmaxf(fmaxf(c0[2], c1[2]), fmaxf(c0[3], c1[3])));
      v = fmaxf(v, __shfl_xor(v, 16));
      v = fmaxf(v, __shfl_xor(v, 32));
      macc[ct] += v;
    }
    __syncthreads();
  }

  // ---- partial outputs ----
  if (lane < 16) {
#pragma unroll
    for (int ct = 0; ct < 4; ++ct)
      ws_bm[p * 256 + wv * 64 + ct * 16 + lane] = macc[ct];
  }
  if (jg == 0) s_collred[n] = collacc;
  __syncthreads();
  if (tid == 0) {
    float c = 0.f;
    for (int i = 0; i < NN; ++i) c += s_collred[i];
    ws_bm[WS_SC_OFF + p * 8 + 5] = c;
  }
}

// ---------------- kernel 2: combine + decoder + score -----------------------
__global__ void combine_kernel(const float* __restrict__ ws,
                               const float* __restrict__ enc_b2,
                               const float* __restrict__ dec_w1,
                               const float* __restrict__ dec_b1,
                               const float* __restrict__ dec_w2,
                               const float* __restrict__ dec_b2,
                               float* __restrict__ out_scores) {
  __shared__ float s_feat[256];
  __shared__ float s_dh[64];
  __shared__ float s_hard[4];
  __shared__ float s_inter[4];
  __shared__ float s_mc[2];  // egosum, coll
  const int bm = blockIdx.x;
  const int tid = threadIdx.x;  // 64 threads
  const float* wb = ws + WS_BASE + (size_t)bm * WS_BM_STRIDE;

  for (int c = tid; c < 256; c += 64) {
    float f = wb[c] + wb[256 + c] + wb[512 + c] + wb[768 + c];
    s_feat[c] = f * (1.f / NT) + enc_b2[c];
  }
  const float* sc = wb + WS_SC_OFF;
  if (tid < 6) {
    float s = sc[tid] + sc[8 + tid] + sc[16 + tid] + sc[24 + tid];
    if (tid == 0) s_hard[0] = -fminf(fmaxf(s * (1.f / NT), 0.f), 15.f) * (1.f / 15.f);
    if (tid == 1) s_hard[1] = fminf(fmaxf(s * (1.f / NT), 0.f), 4.f) * 0.25f;
    if (tid == 2) s_hard[2] = fminf(fmaxf(s * (1.f / NT), 0.f), 6.f) * (1.f / 6.f);
    if (tid == 3) s_hard[3] = fminf(fmaxf(s * (1.f / NT), 0.f), 5.f) * 0.2f;
    if (tid == 4) s_mc[0] = s;
    if (tid == 5) s_mc[1] = s;
  }
  __syncthreads();

  {
    float a0 = 0.f, a1 = 0.f, a2 = 0.f, a3 = 0.f;
    for (int i = 0; i < 256; i += 4) {
      a0 += s_feat[i + 0] * dec_w1[(i + 0) * 64 + tid];
      a1 += s_feat[i + 1] * dec_w1[(i + 1) * 64 + tid];
      a2 += s_feat[i + 2] * dec_w1[(i + 2) * 64 + tid];
      a3 += s_feat[i + 3] * dec_w1[(i + 3) * 64 + tid];
    }
    float acc = dec_b1[tid] + ((a0 + a1) + (a2 + a3));
    s_dh[tid] = acc > 0.f ? acc : expm1f(acc);  // elu
  }
  __syncthreads();

  if (tid < 4) {
    float acc = dec_b2[tid];
    for (int k = 0; k < 64; ++k) acc += s_dh[k] * dec_w2[k * 4 + tid];
    s_inter[tid] = 1.f / (1.f + __expf(-acc));  // sigmoid
  }
  __syncthreads();

  if (tid == 0) {
    const float* wts = ws + WS_WTS;
    float scv = 0.f;
#pragma unroll
    for (int i = 0; i < 4; ++i) scv += s_hard[i] * wts[i];
#pragma unroll
    for (int i = 0; i < 4; ++i) scv += s_inter[i] * wts[4 + i];
    scv = -scv - 10.f * s_mc[1];
    if (s_mc[0] == 0.f) scv = -INFINITY;
    out_scores[bm] = scv;
  }
}

extern "C" void kernel_launch(void* const* d_in, const int* in_sizes, int n_in,
                              void* d_out, int out_size, void* d_ws, size_t ws_size,
                              hipStream_t stream) {
  const float* ego_traj      = (const float*)d_in[0];
  const float* agents_traj   = (const float*)d_in[2];
  const float* agents_states = (const float*)d_in[3];
  const float* enc_w1 = (const float*)d_in[4];
  const float* enc_b1 = (const float*)d_in[5];
  const float* enc_w2 = (const float*)d_in[6];
  const float* enc_b2 = (const float*)d_in[7];
  const float* dec_w1 = (const float*)d_in[8];
  const float* dec_b1 = (const float*)d_in[9];
  const float* dec_w2 = (const float*)d_in[10];
  const float* dec_b2 = (const float*)d_in[11];
  const float* wd_w1 = (const float*)d_in[12];
  const float* wd_b1 = (const float*)d_in[13];
  const float* wd_w2 = (const float*)d_in[14];
  const float* wd_b2 = (const float*)d_in[15];

  float* out = (float*)d_out;
  float* ws = (float*)d_ws;

  weights_kernel<<<1, 64, 0, stream>>>(wd_w1, wd_b1, wd_w2, wd_b2, ws, out);
  score_partial<<<NB * NM * NP, 256, 0, stream>>>(
      ego_traj, agents_traj, agents_states, enc_w1, enc_b1, enc_w2, ws);
  combine_kernel<<<NB * NM, 64, 0, stream>>>(
      ws, enc_b2, dec_w1, dec_b1, dec_w2, dec_b2, out);
}

// Round 4
// 51.520 us; speedup vs baseline: 1.8070x; 1.2567x over previous
//
#include <hip/hip_runtime.h>
#include <hip/hip_bf16.h>
#include <math.h>

typedef __attribute__((ext_vector_type(8))) short bf16x8;
typedef __attribute__((ext_vector_type(4))) float f32x4;

#define NB 16
#define NM 16
#define NN 32
#define NT 80
#define TC 20   // timesteps per partial block
#define NP 4    // partial blocks per (b,m)

// ---- d_ws float layout ----
#define WS_WTS 0
#define WS_BASE 16
#define WS_BM_STRIDE 1056
#define WS_SC_OFF 1024

__device__ __forceinline__ unsigned pk2bf(float lo, float hi) {
  __hip_bfloat162 h = __float22bfloat162_rn(make_float2(lo, hi));  // v_cvt_pk_bf16_f32
  return *reinterpret_cast<unsigned*>(&h);
}
__device__ __forceinline__ short f2bf(float f) {
  unsigned u = __float_as_uint(f);
  u += 0x7fffu + ((u >> 16) & 1u);
  return (short)(u >> 16);
}

// ---------------- kernel 0: weights head (data-independent: enc_in = ones) ---
__global__ void weights_kernel(const float* __restrict__ wd_w1,
                               const float* __restrict__ wd_b1,
                               const float* __restrict__ wd_w2,
                               const float* __restrict__ wd_b2,
                               float* __restrict__ ws,
                               float* __restrict__ out) {
  __shared__ float sh[64];
  int j = threadIdx.x;
  if (j < 64) {
    float acc = wd_b1[j];
    for (int i = 0; i < 256; ++i) acc += wd_w1[i * 64 + j];
    sh[j] = acc > 0.f ? acc : expm1f(acc);  // elu
  }
  __syncthreads();
  if (j < 8) {
    float acc = wd_b2[j];
    for (int k = 0; k < 64; ++k) acc += sh[k] * wd_w2[k * 8 + j];
    float sp = log1pf(__expf(acc));  // softplus
    ws[WS_WTS + j] = sp;
    for (int b = 0; b < NB; ++b) out[NB * NM + b * 8 + j] = sp;  // weights output
  }
}

// ---------------- kernel 1: partial encoder/feature kernel ------------------
// grid = NB*NM*NP, 256 threads. Block (bm, p) handles t in [p*TC, p*TC+TC).
// Rel features deduped into s_rel; 2 timesteps per barrier; (2n x 4j) GEMM1 split.
__global__ __launch_bounds__(256, 4) void score_partial(
    const float* __restrict__ ego_traj,      // [B][M][T][6]
    const float* __restrict__ agents_traj,   // [B][M][N][T][3]
    const float* __restrict__ agents_states, // [B][N][11]
    const float* __restrict__ enc_w1, const float* __restrict__ enc_b1,
    const float* __restrict__ enc_w2,
    float* __restrict__ ws)
{
  __shared__ float s_rel[5][TC][NN];                    // 12.8 KB deduped rel features
  __shared__ __align__(16) short s_hidden[4][NN * 64];  // 16 KB, 4 ping-pong bf16 tiles
  __shared__ float s_ego[TC][5];                        // ex,ey,eh,evx,evy
  __shared__ float s_acc[TC + 2];
  __shared__ float s_spd[TC], s_lat[TC], s_egos[TC];
  __shared__ float s_mask[NN];
  __shared__ float s_collpart[256];
  __shared__ float s_cw[32];

  const int bid = blockIdx.x;
  const int bm = bid >> 2;
  const int p = bid & 3;
  const int t0 = p * TC;
  const int b = bm >> 4;
  const int tid = threadIdx.x;
  const int lane = tid & 63;
  const int wv = tid >> 6;

  float* ws_bm = ws + WS_BASE + (size_t)bm * WS_BM_STRIDE;

  // ---- phase A: ego staging + agent mask ----
  if (tid < TC) {
    int i = tid;
    const float* e = ego_traj + ((size_t)bm * NT + (t0 + i)) * 6;
    float ex = e[0], ey = e[1], eh = e[2], spd = e[3], acc = e[4], cur = e[5];
    s_ego[i][0] = ex; s_ego[i][1] = ey; s_ego[i][2] = eh;
    s_ego[i][3] = spd * __cosf(eh);
    s_ego[i][4] = spd * __sinf(eh);
    s_spd[i] = spd;
    s_acc[i + 1] = acc;
    s_lat[i] = fabsf(spd * spd * cur);
    s_egos[i] = ex + ey + eh + spd + acc + cur;
  } else if (tid == TC) {
    int tp = (p == 0) ? 0 : (t0 - 1);
    s_acc[0] = ego_traj[((size_t)bm * NT + tp) * 6 + 4];
  } else if (tid >= 64 && tid < 64 + NN) {
    int n = tid - 64;
    const float* st = agents_states + ((size_t)b * NN + n) * 11;
    float s = 0.f;
    for (int i = 0; i < 11; ++i) s += st[i];
    s_mask[n] = (s != 0.f) ? 1.f : 0.f;
  }

  // prologue register loads (no LDS deps): enc_w1 cols, enc_w2 B-frags
  const int jq = tid & 15;        // j-quad: j0 = jq*4
  const int nh = tid >> 4;        // 0..15 -> handles n = nh and nh+16
  const int na = nh, nb_ = nh + 16;
  const int j0 = jq * 4;

  float w1r[5][4];
#pragma unroll
  for (int i = 0; i < 5; ++i)
#pragma unroll
    for (int jj = 0; jj < 4; ++jj)
      w1r[i][jj] = enc_w1[i * 64 + j0 + jj];

  bf16x8 Bf[4][2];  // enc_w2 B-frags: wave wv owns cols [wv*64, +64)
  {
    const int colb = lane & 15;
    const int krow = (lane >> 4) * 8;
#pragma unroll
    for (int ct = 0; ct < 4; ++ct) {
      int col = wv * 64 + ct * 16 + colb;
#pragma unroll
      for (int kt = 0; kt < 2; ++kt) {
#pragma unroll
        for (int j = 0; j < 8; ++j) {
          int k = kt * 32 + krow + j;
          Bf[ct][kt][j] = f2bf(enc_w2[k * 256 + col]);
        }
      }
    }
  }
  __syncthreads();  // barrier 1: s_ego/s_mask ready

  // ---- phase B: deduped rel features + coll (each (n,t) pair once) ----
  {
    float collacc = 0.f;
    const float* atraj = agents_traj + (size_t)bm * (NN * NT * 3);
#pragma unroll
    for (int k = 0; k < 3; ++k) {
      int pp = tid + k * 256;
      if (pp < NN * TC) {
        int n = pp / TC;
        int i = pp - n * TC;
        int tg = t0 + i;
        const float* bp = atraj + n * (NT * 3) + tg * 3;
        float ax = bp[0], ay = bp[1], ah = bp[2];
        float avx, avy;
        if (tg == 0) { avx = (bp[3] - ax) * 10.f; avy = (bp[4] - ay) * 10.f; }
        else         { avx = (ax - bp[-3]) * 10.f; avy = (ay - bp[-2]) * 10.f; }
        float ex = s_ego[i][0], ey = s_ego[i][1], eh = s_ego[i][2];
        float evx = s_ego[i][3], evy = s_ego[i][4];
        float m = s_mask[n];
        float ryr = ah - eh;
        float w = ryr - 6.283185307179586f * rintf(ryr * 0.15915494309189535f);
        float cy = __cosf(ryr), sy = __sinf(ryr);
        float dx = ax - ex, dy = ay - ey;
        s_rel[0][i][n] = dx * cy * m;
        s_rel[1][i][n] = dy * sy * m;
        s_rel[2][i][n] = w * m;
        s_rel[3][i][n] = (avx - evx) * cy * m;
        s_rel[4][i][n] = (avy - evy) * sy * m;
        collacc += __expf(-0.2f * (dx * dx + dy * dy)) * m;
      }
    }
    s_collpart[tid] = collacc;
  }

  // hard-feature partial sums on high tids (they have only 2 rel pairs)
  if (tid >= 251) {
    int which = tid - 251;
    float s = 0.f;
    if (which == 0)      { for (int i = 0; i < TC; ++i) s += s_spd[i]; }
    else if (which == 1) { for (int i = 0; i < TC; ++i) s += fabsf(s_acc[i + 1]); }
    else if (which == 2) {
      for (int i = 0; i < TC; ++i) {
        int ia = (p == 0 && i == 0) ? 2 : (i + 1);
        s += fabsf((s_acc[ia] - s_acc[ia - 1]) * 10.f);
      }
    }
    else if (which == 3) { for (int i = 0; i < TC; ++i) s += s_lat[i]; }
    else                 { for (int i = 0; i < TC; ++i) s += s_egos[i]; }
    ws_bm[WS_SC_OFF + p * 8 + which] = s;
  }

  // baseB = mask * (agent_states[6:11] @ enc_w1[5:10]) + enc_b1, for both n's
  float baseA[4], baseBB[4];
#pragma unroll
  for (int half = 0; half < 2; ++half) {
    int n = half ? nb_ : na;
    const float* st = agents_states + ((size_t)b * NN + n) * 11 + 6;
    float m = s_mask[n];
    float a0 = st[0], a1 = st[1], a2 = st[2], a3 = st[3], a4 = st[4];
#pragma unroll
    for (int jj = 0; jj < 4; ++jj) {
      float acc = a0 * enc_w1[5 * 64 + j0 + jj] + a1 * enc_w1[6 * 64 + j0 + jj] +
                  a2 * enc_w1[7 * 64 + j0 + jj] + a3 * enc_w1[8 * 64 + j0 + jj] +
                  a4 * enc_w1[9 * 64 + j0 + jj];
      float v = m * acc + enc_b1[j0 + jj];
      if (half) baseBB[jj] = v; else baseA[jj] = v;
    }
  }

  // swizzled hidden-tile addresses (G4: byte ^= (row&7)<<4)
  const int wbyteA = (na * 128 + jq * 8) ^ ((na & 7) << 4);
  const int wbyteB = (nb_ * 128 + jq * 8) ^ ((nb_ & 7) << 4);
  int abyte[2][2];
  {
    int nbl = lane & 15;
    int kb = (lane >> 4) * 16;
#pragma unroll
    for (int rt = 0; rt < 2; ++rt) {
      int row = rt * 16 + nbl;
#pragma unroll
      for (int kt = 0; kt < 2; ++kt)
        abyte[rt][kt] = (row * 128 + kt * 64 + kb) ^ ((row & 7) << 4);
    }
  }

  // GEMM1 for local t=i -> swizzled bf16 tile in s_hidden[buf]
  auto compute_hidden = [&](int i, int buf) {
    float r0a = s_rel[0][i][na], r1a = s_rel[1][i][na], r2a = s_rel[2][i][na],
          r3a = s_rel[3][i][na], r4a = s_rel[4][i][na];
    float r0b = s_rel[0][i][nb_], r1b = s_rel[1][i][nb_], r2b = s_rel[2][i][nb_],
          r3b = s_rel[3][i][nb_], r4b = s_rel[4][i][nb_];
    float pa[4], pb[4];
#pragma unroll
    for (int jj = 0; jj < 4; ++jj) {
      pa[jj] = fmaxf(baseA[jj] + r0a * w1r[0][jj] + r1a * w1r[1][jj] +
                     r2a * w1r[2][jj] + r3a * w1r[3][jj] + r4a * w1r[4][jj], 0.f);
      pb[jj] = fmaxf(baseBB[jj] + r0b * w1r[0][jj] + r1b * w1r[1][jj] +
                     r2b * w1r[2][jj] + r3b * w1r[3][jj] + r4b * w1r[4][jj], 0.f);
    }
    char* hb = reinterpret_cast<char*>(&s_hidden[buf][0]);
    uint2 ua = {pk2bf(pa[0], pa[1]), pk2bf(pa[2], pa[3])};
    uint2 ub = {pk2bf(pb[0], pb[1]), pk2bf(pb[2], pb[3])};
    *reinterpret_cast<uint2*>(hb + wbyteA) = ua;
    *reinterpret_cast<uint2*>(hb + wbyteB) = ub;
  };

  float macc[4] = {0.f, 0.f, 0.f, 0.f};

  // MFMA + max-over-n + accumulate for one staged tile
  auto mfma_step = [&](int buf) {
    const char* hb = reinterpret_cast<const char*>(&s_hidden[buf][0]);
    bf16x8 a00 = *reinterpret_cast<const bf16x8*>(hb + abyte[0][0]);
    bf16x8 a01 = *reinterpret_cast<const bf16x8*>(hb + abyte[0][1]);
    bf16x8 a10 = *reinterpret_cast<const bf16x8*>(hb + abyte[1][0]);
    bf16x8 a11 = *reinterpret_cast<const bf16x8*>(hb + abyte[1][1]);
#pragma unroll
    for (int ct = 0; ct < 4; ++ct) {
      f32x4 c0 = {0.f, 0.f, 0.f, 0.f}, c1 = {0.f, 0.f, 0.f, 0.f};
      c0 = __builtin_amdgcn_mfma_f32_16x16x32_bf16(a00, Bf[ct][0], c0, 0, 0, 0);
      c0 = __builtin_amdgcn_mfma_f32_16x16x32_bf16(a01, Bf[ct][1], c0, 0, 0, 0);
      c1 = __builtin_amdgcn_mfma_f32_16x16x32_bf16(a10, Bf[ct][0], c1, 0, 0, 0);
      c1 = __builtin_amdgcn_mfma_f32_16x16x32_bf16(a11, Bf[ct][1], c1, 0, 0, 0);
      float v = fmaxf(fmaxf(fmaxf(c0[0], c1[0]), fmaxf(c0[1], c1[1])),
                      fmaxf(fmaxf(c0[2], c1[2]), fmaxf(c0[3], c1[3])));
      v = fmaxf(v, __shfl_xor(v, 16));
      v = fmaxf(v, __shfl_xor(v, 32));
      macc[ct] += v;
    }
  };

  __syncthreads();  // barrier 2: s_rel ready
  compute_hidden(0, 0);
  compute_hidden(1, 1);
  __syncthreads();  // barrier 3: bufs 0,1 ready

  for (int i = 0; i < TC; i += 2) {
    mfma_step(i & 3);
    mfma_step((i + 1) & 3);
    if (i + 2 < TC) compute_hidden(i + 2, (i + 2) & 3);
    if (i + 3 < TC) compute_hidden(i + 3, (i + 3) & 3);
    __syncthreads();  // bufs (i+2)&3,(i+3)&3 ready; (i)&3,(i+1)&3 free next iter
  }

  // ---- partial outputs ----
  if (lane < 16) {
#pragma unroll
    for (int ct = 0; ct < 4; ++ct)
      ws_bm[p * 256 + wv * 64 + ct * 16 + lane] = macc[ct];
  }
  if (tid < 32) {
    float s = 0.f;
#pragma unroll
    for (int k = 0; k < 8; ++k) s += s_collpart[tid + k * 32];
    s_cw[tid] = s;
  }
  __syncthreads();
  if (tid == 0) {
    float c = 0.f;
    for (int i = 0; i < 32; ++i) c += s_cw[i];
    ws_bm[WS_SC_OFF + p * 8 + 5] = c;
  }
}

// ---------------- kernel 2: combine + decoder + score -----------------------
__global__ void combine_kernel(const float* __restrict__ ws,
                               const float* __restrict__ enc_b2,
                               const float* __restrict__ dec_w1,
                               const float* __restrict__ dec_b1,
                               const float* __restrict__ dec_w2,
                               const float* __restrict__ dec_b2,
                               float* __restrict__ out_scores) {
  __shared__ float s_feat[256];
  __shared__ float s_dh[64];
  __shared__ float s_hard[4];
  __shared__ float s_inter[4];
  __shared__ float s_mc[2];  // egosum, coll
  const int bm = blockIdx.x;
  const int tid = threadIdx.x;  // 64 threads
  const float* wb = ws + WS_BASE + (size_t)bm * WS_BM_STRIDE;

  for (int c = tid; c < 256; c += 64) {
    float f = wb[c] + wb[256 + c] + wb[512 + c] + wb[768 + c];
    s_feat[c] = f * (1.f / NT) + enc_b2[c];
  }
  const float* sc = wb + WS_SC_OFF;
  if (tid < 6) {
    float s = sc[tid] + sc[8 + tid] + sc[16 + tid] + sc[24 + tid];
    if (tid == 0) s_hard[0] = -fminf(fmaxf(s * (1.f / NT), 0.f), 15.f) * (1.f / 15.f);
    if (tid == 1) s_hard[1] = fminf(fmaxf(s * (1.f / NT), 0.f), 4.f) * 0.25f;
    if (tid == 2) s_hard[2] = fminf(fmaxf(s * (1.f / NT), 0.f), 6.f) * (1.f / 6.f);
    if (tid == 3) s_hard[3] = fminf(fmaxf(s * (1.f / NT), 0.f), 5.f) * 0.2f;
    if (tid == 4) s_mc[0] = s;
    if (tid == 5) s_mc[1] = s;
  }
  __syncthreads();

  {
    float a0 = 0.f, a1 = 0.f, a2 = 0.f, a3 = 0.f;
    for (int i = 0; i < 256; i += 4) {
      a0 += s_feat[i + 0] * dec_w1[(i + 0) * 64 + tid];
      a1 += s_feat[i + 1] * dec_w1[(i + 1) * 64 + tid];
      a2 += s_feat[i + 2] * dec_w1[(i + 2) * 64 + tid];
      a3 += s_feat[i + 3] * dec_w1[(i + 3) * 64 + tid];
    }
    float acc = dec_b1[tid] + ((a0 + a1) + (a2 + a3));
    s_dh[tid] = acc > 0.f ? acc : expm1f(acc);  // elu
  }
  __syncthreads();

  if (tid < 4) {
    float acc = dec_b2[tid];
    for (int k = 0; k < 64; ++k) acc += s_dh[k] * dec_w2[k * 4 + tid];
    s_inter[tid] = 1.f / (1.f + __expf(-acc));  // sigmoid
  }
  __syncthreads();

  if (tid == 0) {
    const float* wts = ws + WS_WTS;
    float scv = 0.f;
#pragma unroll
    for (int i = 0; i < 4; ++i) scv += s_hard[i] * wts[i];
#pragma unroll
    for (int i = 0; i < 4; ++i) scv += s_inter[i] * wts[4 + i];
    scv = -scv - 10.f * s_mc[1];
    if (s_mc[0] == 0.f) scv = -INFINITY;
    out_scores[bm] = scv;
  }
}

extern "C" void kernel_launch(void* const* d_in, const int* in_sizes, int n_in,
                              void* d_out, int out_size, void* d_ws, size_t ws_size,
                              hipStream_t stream) {
  const float* ego_traj      = (const float*)d_in[0];
  const float* agents_traj   = (const float*)d_in[2];
  const float* agents_states = (const float*)d_in[3];
  const float* enc_w1 = (const float*)d_in[4];
  const float* enc_b1 = (const float*)d_in[5];
  const float* enc_w2 = (const float*)d_in[6];
  const float* enc_b2 = (const float*)d_in[7];
  const float* dec_w1 = (const float*)d_in[8];
  const float* dec_b1 = (const float*)d_in[9];
  const float* dec_w2 = (const float*)d_in[10];
  const float* dec_b2 = (const float*)d_in[11];
  const float* wd_w1 = (const float*)d_in[12];
  const float* wd_b1 = (const float*)d_in[13];
  const float* wd_w2 = (const float*)d_in[14];
  const float* wd_b2 = (const float*)d_in[15];

  float* out = (float*)d_out;
  float* ws = (float*)d_ws;

  weights_kernel<<<1, 64, 0, stream>>>(wd_w1, wd_b1, wd_w2, wd_b2, ws, out);
  score_partial<<<NB * NM * NP, 256, 0, stream>>>(
      ego_traj, agents_traj, agents_states, enc_w1, enc_b1, enc_w2, ws);
  combine_kernel<<<NB * NM, 64, 0, stream>>>(
      ws, enc_b2, dec_w1, dec_b1, dec_w2, dec_b2, out);
}